// Round 9
// baseline (484.639 us; speedup 1.0000x reference)
//
#include <hip/hip_runtime.h>
#include <hip/hip_fp16.h>
#include <stdint.h>

#define NEG_SLOPE 0.2f
typedef _Float16 half_t;

static inline int ceil_div(int a, int b){ return (a + b - 1) / b; }

// ---------------------------------------------------------------- CSR build
__global__ __launch_bounds__(256) void zero_i32(int* __restrict__ p, int n){
  int i = blockIdx.x * 256 + threadIdx.x;
  if (i < n) p[i] = 0;
}

// 4 edges/thread: one int4 load + 4 independent atomics in flight
__global__ __launch_bounds__(256) void hist_kernel(const int* __restrict__ dst,
                                                   int* __restrict__ counts, int E){
  int i0 = (blockIdx.x * 256 + threadIdx.x) * 4;
  if (i0 + 3 < E){
    int4 d = *(const int4*)(dst + i0);
    atomicAdd(counts + d.x, 1);
    atomicAdd(counts + d.y, 1);
    atomicAdd(counts + d.z, 1);
    atomicAdd(counts + d.w, 1);
  } else {
    for (int i = i0; i < E; ++i) atomicAdd(counts + dst[i], 1);
  }
}

// single-block exclusive scan of counts[n] -> offsets[n+1], cursor[n]
__global__ __launch_bounds__(1024) void scan_kernel(const int* __restrict__ counts,
                                                    int* __restrict__ offsets,
                                                    int* __restrict__ cursor, int n){
  __shared__ int lds[1024];
  const int tid = threadIdx.x;
  const int chunk = (n + 1023) >> 10;
  const int beg = tid * chunk;
  const int end = min(beg + chunk, n);
  int s = 0;
  for (int i = beg; i < end; ++i) s += counts[i];
  lds[tid] = s;
  __syncthreads();
  for (int off = 1; off < 1024; off <<= 1){
    int t = 0;
    if (tid >= off) t = lds[tid - off];
    __syncthreads();
    if (tid >= off) lds[tid] += t;
    __syncthreads();
  }
  int run = lds[tid] - s;
  for (int i = beg; i < end; ++i){
    offsets[i] = run;
    cursor[i]  = run;
    run += counts[i];
  }
  if (tid == 1023) offsets[n] = lds[1023];
}

// 4 edges/thread: int4 loads, 4 atomic-returns in flight
__global__ __launch_bounds__(256) void scatter_kernel(const int* __restrict__ srcv,
                                                      const int* __restrict__ dstv,
                                                      int* __restrict__ cursor,
                                                      int* __restrict__ sorted_src, int E){
  int i0 = (blockIdx.x * 256 + threadIdx.x) * 4;
  if (i0 + 3 < E){
    int4 s = *(const int4*)(srcv + i0);
    int4 d = *(const int4*)(dstv + i0);
    int p0 = atomicAdd(cursor + d.x, 1);
    int p1 = atomicAdd(cursor + d.y, 1);
    int p2 = atomicAdd(cursor + d.z, 1);
    int p3 = atomicAdd(cursor + d.w, 1);
    if (p0 >= 0 && p0 < E) sorted_src[p0] = s.x;   // clamps: rocprof replay safety
    if (p1 >= 0 && p1 < E) sorted_src[p1] = s.y;
    if (p2 >= 0 && p2 < E) sorted_src[p2] = s.z;
    if (p3 >= 0 && p3 < E) sorted_src[p3] = s.w;
  } else {
    for (int i = i0; i < E; ++i){
      int d = dstv[i];
      int pos = atomicAdd(cursor + d, 1);
      if (pos >= 0 && pos < E) sorted_src[pos] = srcv[i];
    }
  }
}

// ------------------------------------------------- per-layer: h = x@W (+ fused a·h)
// fp32 in / fp32 compute; h stored fp16 (RTNE), natural channel order.
__global__ __launch_bounds__(256) void gemm_fused(const float* __restrict__ x,
                                                  const float* __restrict__ W,
                                                  const float* __restrict__ a_src,
                                                  const float* __restrict__ a_dst,
                                                  half_t* __restrict__ h,
                                                  float* __restrict__ s_src,
                                                  float* __restrict__ s_dst, int N){
  __shared__ float xlds[16 * 64];
  const int tid  = threadIdx.x;
  const int lane = tid & 63;
  const int wave = tid >> 6;
  const int row0 = blockIdx.x * 16;

  float wreg[64];
  #pragma unroll
  for (int k = 0; k < 64; ++k) wreg[k] = W[k * 64 + lane];

  {
    const float4* xg = (const float4*)x;
    int r = row0 + (tid >> 4);
    float4 v = {0.f, 0.f, 0.f, 0.f};
    if (r < N) v = xg[(size_t)r * 16 + (tid & 15)];
    ((float4*)xlds)[tid] = v;
  }
  __syncthreads();

  const float asv = a_src[lane];
  const float adv = a_dst[lane];

  for (int r = wave; r < 16; r += 4){
    int row = row0 + r;
    if (row >= N) break;               // uniform within wave
    const float4* xr = (const float4*)(xlds + r * 64);
    float a0 = 0.0f, a1 = 0.0f;
    #pragma unroll
    for (int kk = 0; kk < 8; ++kk){
      float4 xv = xr[kk];
      a0 = fmaf(xv.x, wreg[4*kk+0], a0);
      a0 = fmaf(xv.y, wreg[4*kk+1], a0);
      a0 = fmaf(xv.z, wreg[4*kk+2], a0);
      a0 = fmaf(xv.w, wreg[4*kk+3], a0);
    }
    #pragma unroll
    for (int kk = 8; kk < 16; ++kk){
      float4 xv = xr[kk];
      a1 = fmaf(xv.x, wreg[4*kk+0], a1);
      a1 = fmaf(xv.y, wreg[4*kk+1], a1);
      a1 = fmaf(xv.z, wreg[4*kk+2], a1);
      a1 = fmaf(xv.w, wreg[4*kk+3], a1);
    }
    float acc = a0 + a1;
    h[(size_t)row * 64 + lane] = (half_t)acc;
    float ps = acc * asv;
    float pd = acc * adv;
    #pragma unroll
    for (int off = 1; off < 8; off <<= 1){
      ps += __shfl_xor(ps, off, 64);
      pd += __shfl_xor(pd, off, 64);
    }
    if ((lane & 7) == 0){
      s_src[row * 8 + (lane >> 3)] = ps;
      s_dst[row * 8 + (lane >> 3)] = pd;
    }
  }
}

// ------------------------------------- per-layer: segment softmax + aggregation
// one wave per node; lane = e8*8 + c8 (c8 = head, e8 = edge slot).
// TA-address-minimized gathers per edge: 1 idx lane-addr (single-lane load +
// shfl broadcast), 4 score lane-addrs (4x float2 coop + shfl distribute),
// 8 h lane-addrs (fp16 row = 8 lanes x 16B). Was 24, now 13.
__global__ __launch_bounds__(256) void aggregate(const half_t* __restrict__ h,
                                                 const float* __restrict__ s_src,
                                                 const float* __restrict__ s_dst,
                                                 const int* __restrict__ offsets,
                                                 const int* __restrict__ sorted_src,
                                                 const float* __restrict__ bias,
                                                 float* __restrict__ out,
                                                 int N, int E){
  const int node = (blockIdx.x * 256 + threadIdx.x) >> 6;
  if (node >= N) return;
  const int lane = threadIdx.x & 63;
  const int c8 = lane & 7;            // head / channel group
  const int e8 = lane >> 3;           // edge slot
  const int gbase = lane & ~7;        // first lane of this edge group
  // clamp against rocprof dispatch-replay with poisoned workspace
  int beg = offsets[node];
  int end = offsets[node + 1];
  beg = max(0, min(beg, E));
  end = max(0, min(end, E));
  const int nv = end - beg + 1;       // +1 self-loop (slot 0)
  const float sdst = s_dst[node * 8 + c8];

  float m = -3.0e38f;
  float z = 0.0f;
  float acc[8];
  #pragma unroll
  for (int j = 0; j < 8; ++j) acc[j] = 0.0f;

  union Cvt { float4 f4; half_t hx[8]; };

  if (nv <= 64){
    const int cnt = (e8 < nv) ? ((nv - e8 + 7) >> 3) : 0;
    // phase 1: edge indices -- ONE lane per group loads, broadcast via shfl
    int sidx[8];
    #pragma unroll
    for (int j = 0; j < 8; ++j){
      int v = e8 + 8 * j;
      int my = node;                                  // self-loop (v==0)
      if (j < cnt && c8 == 0 && v != 0) my = sorted_src[beg + v - 1];
      int b = __shfl(my, gbase, 64);
      if (j < cnt) sidx[j] = b;
    }
    // phase 2: score rows -- lanes c8<4 load float2, shfl-distribute
    float sc[8];
    #pragma unroll
    for (int j = 0; j < 8; ++j){
      float2 f2 = {0.f, 0.f};
      if (j < cnt && c8 < 4)
        f2 = *(const float2*)(s_src + (size_t)sidx[j] * 8 + c8 * 2);
      float vx = __shfl(f2.x, gbase + (c8 >> 1), 64);
      float vy = __shfl(f2.y, gbase + (c8 >> 1), 64);
      if (j < cnt){
        float s = ((c8 & 1) ? vy : vx) + sdst;
        sc[j] = (s > 0.0f) ? s : NEG_SLOPE * s;
      }
    }
    // phase 2b: h gathers (one 16B load per slot) before the butterfly
    float4 hraw[8];
    #pragma unroll
    for (int j = 0; j < 8; ++j){
      if (j < cnt)
        hraw[j] = *(const float4*)(h + (size_t)sidx[j] * 64 + c8 * 8);
    }
    // per-head max + butterfly
    #pragma unroll
    for (int j = 0; j < 8; ++j)
      if (j < cnt) m = fmaxf(m, sc[j]);
    m = fmaxf(m, __shfl_xor(m, 8, 64));
    m = fmaxf(m, __shfl_xor(m, 16, 64));
    m = fmaxf(m, __shfl_xor(m, 32, 64));
    // phase 3: convert + accumulate (pure VALU)
    #pragma unroll
    for (int j = 0; j < 8; ++j){
      if (j < cnt){
        float e = __expf(sc[j] - m);
        z += e;
        Cvt u; u.f4 = hraw[j];
        #pragma unroll
        for (int k = 0; k < 8; ++k)
          acc[k] = fmaf(e, (float)u.hx[k], acc[k]);
      }
    }
  } else {
    // slow streaming path (rare: nv > 64)
    for (int v = e8; v < nv; v += 8){
      int s = (v == 0) ? node : sorted_src[beg + v - 1];
      float scv = s_src[s * 8 + c8] + sdst;
      scv = (scv > 0.0f) ? scv : NEG_SLOPE * scv;
      m = fmaxf(m, scv);
    }
    m = fmaxf(m, __shfl_xor(m, 8, 64));
    m = fmaxf(m, __shfl_xor(m, 16, 64));
    m = fmaxf(m, __shfl_xor(m, 32, 64));
    for (int v = e8; v < nv; v += 8){
      int s = (v == 0) ? node : sorted_src[beg + v - 1];
      float scv = s_src[s * 8 + c8] + sdst;
      scv = (scv > 0.0f) ? scv : NEG_SLOPE * scv;
      float e = __expf(scv - m);
      z += e;
      Cvt u; u.f4 = *(const float4*)(h + (size_t)s * 64 + c8 * 8);
      #pragma unroll
      for (int k = 0; k < 8; ++k)
        acc[k] = fmaf(e, (float)u.hx[k], acc[k]);
    }
  }

  // butterfly reduce z + acc over the 8 e8-groups
  #pragma unroll
  for (int off = 8; off < 64; off <<= 1){
    z += __shfl_xor(z, off, 64);
    #pragma unroll
    for (int j = 0; j < 8; ++j) acc[j] += __shfl_xor(acc[j], off, 64);
  }

  if (e8 == 0){
    float inv = 1.0f / (z + 1e-16f);
    const float4* bp = (const float4*)(bias + c8 * 8);
    float4 b0 = bp[0], b1 = bp[1];
    float4 o0, o1;
    o0.x = acc[0] * inv + b0.x;
    o0.y = acc[1] * inv + b0.y;
    o0.z = acc[2] * inv + b0.z;
    o0.w = acc[3] * inv + b0.w;
    o1.x = acc[4] * inv + b1.x;
    o1.y = acc[5] * inv + b1.y;
    o1.z = acc[6] * inv + b1.z;
    o1.w = acc[7] * inv + b1.w;
    float4* op = (float4*)(out + (size_t)node * 64 + c8 * 8);
    op[0] = o0;
    op[1] = o1;
  }
}

// ---------------------------------------------------------------- launch
extern "C" void kernel_launch(void* const* d_in, const int* in_sizes, int n_in,
                              void* d_out, int out_size, void* d_ws, size_t ws_size,
                              hipStream_t stream){
  const float* x0   = (const float*)d_in[0];
  const int*   eidx = (const int*)  d_in[1];   // [2, E]
  const float* Ws   = (const float*)d_in[2];   // [L, 64, 64]
  const float* asrc = (const float*)d_in[3];   // [L, 8, 8]
  const float* adst = (const float*)d_in[4];   // [L, 8, 8]
  const float* bias = (const float*)d_in[5];   // [L, 64]

  const int N = in_sizes[0] / 64;
  const int E = in_sizes[1] / 2;
  const int L = in_sizes[2] / (64 * 64);

  char* ws = (char*)d_ws;
  size_t off = 0;
  auto alloc = [&](size_t bytes) -> void* {
    void* p = ws + off;
    off = (off + bytes + 255) & ~(size_t)255;
    return p;
  };
  half_t* hbuf   = (half_t*)alloc((size_t)N * 64 * sizeof(half_t));
  float* bufA    = (float*)alloc((size_t)N * 64 * sizeof(float));
  float* bufB    = (float*)alloc((size_t)N * 64 * sizeof(float));
  float* ssrc    = (float*)alloc((size_t)N * 8 * sizeof(float));
  float* sdstb   = (float*)alloc((size_t)N * 8 * sizeof(float));
  int*   counts  = (int*)alloc((size_t)N * sizeof(int));
  int*   offsets = (int*)alloc((size_t)(N + 1) * sizeof(int));
  int*   cursor  = (int*)alloc((size_t)N * sizeof(int));
  int*   ssorted = (int*)alloc((size_t)E * sizeof(int));

  const int* esrc = eidx;
  const int* edst = eidx + E;

  // CSR by destination — built once, reused by all layers
  zero_i32<<<ceil_div(N, 256), 256, 0, stream>>>(counts, N);
  hist_kernel<<<ceil_div(E, 1024), 256, 0, stream>>>(edst, counts, E);
  scan_kernel<<<1, 1024, 0, stream>>>(counts, offsets, cursor, N);
  scatter_kernel<<<ceil_div(E, 1024), 256, 0, stream>>>(esrc, edst, cursor, ssorted, E);

  float* bufs[2] = {bufA, bufB};
  for (int l = 0; l < L; ++l){
    const float* xin  = (l == 0)     ? x0 : bufs[(l - 1) & 1];
    float*       xout = (l == L - 1) ? (float*)d_out : bufs[l & 1];
    gemm_fused<<<ceil_div(N, 16), 256, 0, stream>>>(
        xin, Ws + (size_t)l * 64 * 64, asrc + l * 64, adst + l * 64,
        hbuf, ssrc, sdstb, N);
    aggregate<<<ceil_div(N * 64, 256), 256, 0, stream>>>(
        hbuf, ssrc, sdstb, offsets, ssorted, bias + l * 64, xout, N, E);
  }
}

// Round 10
// 452.522 us; speedup vs baseline: 1.0710x; 1.0710x over previous
//
#include <hip/hip_runtime.h>
#include <hip/hip_fp16.h>
#include <stdint.h>

#define NEG_SLOPE 0.2f
typedef _Float16 half_t;
typedef float  f32x4 __attribute__((ext_vector_type(4)));
typedef int    i32x4 __attribute__((ext_vector_type(4)));

static inline int ceil_div(int a, int b){ return (a + b - 1) / b; }

// ---------------------------------------------------------------- CSR build
__global__ __launch_bounds__(256) void zero_i32(int* __restrict__ p, int n){
  int i = blockIdx.x * 256 + threadIdx.x;
  if (i < n) p[i] = 0;
}

// 4 edges/thread: one nt int4 load + 4 independent atomics in flight
__global__ __launch_bounds__(256) void hist_kernel(const int* __restrict__ dst,
                                                   int* __restrict__ counts, int E){
  int i0 = (blockIdx.x * 256 + threadIdx.x) * 4;
  if (i0 + 3 < E){
    i32x4 d = __builtin_nontemporal_load((const i32x4*)(dst + i0));
    atomicAdd(counts + d.x, 1);
    atomicAdd(counts + d.y, 1);
    atomicAdd(counts + d.z, 1);
    atomicAdd(counts + d.w, 1);
  } else {
    for (int i = i0; i < E; ++i) atomicAdd(counts + dst[i], 1);
  }
}

// single-block exclusive scan of counts[n] -> offsets[n+1], cursor[n]
__global__ __launch_bounds__(1024) void scan_kernel(const int* __restrict__ counts,
                                                    int* __restrict__ offsets,
                                                    int* __restrict__ cursor, int n){
  __shared__ int lds[1024];
  const int tid = threadIdx.x;
  const int chunk = (n + 1023) >> 10;
  const int beg = tid * chunk;
  const int end = min(beg + chunk, n);
  int s = 0;
  for (int i = beg; i < end; ++i) s += counts[i];
  lds[tid] = s;
  __syncthreads();
  for (int off = 1; off < 1024; off <<= 1){
    int t = 0;
    if (tid >= off) t = lds[tid - off];
    __syncthreads();
    if (tid >= off) lds[tid] += t;
    __syncthreads();
  }
  int run = lds[tid] - s;
  for (int i = beg; i < end; ++i){
    offsets[i] = run;
    cursor[i]  = run;
    run += counts[i];
  }
  if (tid == 1023) offsets[n] = lds[1023];
}

// 4 edges/thread: nt int4 loads, 4 atomic-returns in flight
__global__ __launch_bounds__(256) void scatter_kernel(const int* __restrict__ srcv,
                                                      const int* __restrict__ dstv,
                                                      int* __restrict__ cursor,
                                                      int* __restrict__ sorted_src, int E){
  int i0 = (blockIdx.x * 256 + threadIdx.x) * 4;
  if (i0 + 3 < E){
    i32x4 s = __builtin_nontemporal_load((const i32x4*)(srcv + i0));
    i32x4 d = __builtin_nontemporal_load((const i32x4*)(dstv + i0));
    int p0 = atomicAdd(cursor + d.x, 1);
    int p1 = atomicAdd(cursor + d.y, 1);
    int p2 = atomicAdd(cursor + d.z, 1);
    int p3 = atomicAdd(cursor + d.w, 1);
    if (p0 >= 0 && p0 < E) sorted_src[p0] = s.x;   // clamps: rocprof replay safety
    if (p1 >= 0 && p1 < E) sorted_src[p1] = s.y;
    if (p2 >= 0 && p2 < E) sorted_src[p2] = s.z;
    if (p3 >= 0 && p3 < E) sorted_src[p3] = s.w;
  } else {
    for (int i = i0; i < E; ++i){
      int d = dstv[i];
      int pos = atomicAdd(cursor + d, 1);
      if (pos >= 0 && pos < E) sorted_src[pos] = srcv[i];
    }
  }
}

// ------------------------------------------------- per-layer: h = x@W (+ fused a·h)
// fp32 in / fp32 compute; h stored fp16 (RTNE), natural order.
// x is once-per-layer streaming -> NONTEMPORAL loads (keep h/scores L2-resident).
__global__ __launch_bounds__(256) void gemm_fused(const float* __restrict__ x,
                                                  const float* __restrict__ W,
                                                  const float* __restrict__ a_src,
                                                  const float* __restrict__ a_dst,
                                                  half_t* __restrict__ h,
                                                  float* __restrict__ s_src,
                                                  float* __restrict__ s_dst, int N){
  __shared__ float xlds[16 * 64];
  const int tid  = threadIdx.x;
  const int lane = tid & 63;
  const int wave = tid >> 6;
  const int row0 = blockIdx.x * 16;

  float wreg[64];
  #pragma unroll
  for (int k = 0; k < 64; ++k) wreg[k] = W[k * 64 + lane];   // temporal: W is hot

  {
    int r = row0 + (tid >> 4);
    f32x4 v = {0.f, 0.f, 0.f, 0.f};
    if (r < N) v = __builtin_nontemporal_load(
        (const f32x4*)(x + (size_t)r * 64 + (tid & 15) * 4));
    ((f32x4*)xlds)[tid] = v;
  }
  __syncthreads();

  const float asv = a_src[lane];
  const float adv = a_dst[lane];

  for (int r = wave; r < 16; r += 4){
    int row = row0 + r;
    if (row >= N) break;               // uniform within wave
    const f32x4* xr = (const f32x4*)(xlds + r * 64);
    float a0 = 0.0f, a1 = 0.0f;
    #pragma unroll
    for (int kk = 0; kk < 8; ++kk){
      f32x4 xv = xr[kk];
      a0 = fmaf(xv.x, wreg[4*kk+0], a0);
      a0 = fmaf(xv.y, wreg[4*kk+1], a0);
      a0 = fmaf(xv.z, wreg[4*kk+2], a0);
      a0 = fmaf(xv.w, wreg[4*kk+3], a0);
    }
    #pragma unroll
    for (int kk = 8; kk < 16; ++kk){
      f32x4 xv = xr[kk];
      a1 = fmaf(xv.x, wreg[4*kk+0], a1);
      a1 = fmaf(xv.y, wreg[4*kk+1], a1);
      a1 = fmaf(xv.z, wreg[4*kk+2], a1);
      a1 = fmaf(xv.w, wreg[4*kk+3], a1);
    }
    float acc = a0 + a1;
    h[(size_t)row * 64 + lane] = (half_t)acc;   // temporal: gathered ~33x next kernel
    float ps = acc * asv;
    float pd = acc * adv;
    #pragma unroll
    for (int off = 1; off < 8; off <<= 1){
      ps += __shfl_xor(ps, off, 64);
      pd += __shfl_xor(pd, off, 64);
    }
    if ((lane & 7) == 0){
      s_src[row * 8 + (lane >> 3)] = ps;        // temporal: gathered next kernel
      s_dst[row * 8 + (lane >> 3)] = pd;
    }
  }
}

// ------------------------------------- per-layer: segment softmax + aggregation
// one wave per node; lane = e8*8 + c8 (c8 = head, e8 = edge slot).
// Gathers (h, s_src) stay TEMPORAL (want L2 residency); streaming accesses
// (sorted_src read, out store) are NONTEMPORAL so they don't evict the hot set.
__global__ __launch_bounds__(256) void aggregate(const half_t* __restrict__ h,
                                                 const float* __restrict__ s_src,
                                                 const float* __restrict__ s_dst,
                                                 const int* __restrict__ offsets,
                                                 const int* __restrict__ sorted_src,
                                                 const float* __restrict__ bias,
                                                 float* __restrict__ out,
                                                 int N, int E){
  const int node = (blockIdx.x * 256 + threadIdx.x) >> 6;
  if (node >= N) return;
  const int lane = threadIdx.x & 63;
  const int c8 = lane & 7;            // head / channel group
  const int e8 = lane >> 3;           // edge slot
  // clamp against rocprof dispatch-replay with poisoned workspace
  int beg = offsets[node];
  int end = offsets[node + 1];
  beg = max(0, min(beg, E));
  end = max(0, min(end, E));
  const int nv = end - beg + 1;       // +1 self-loop (slot 0)
  const float sdst = s_dst[node * 8 + c8];

  float m = -3.0e38f;
  float z = 0.0f;
  float acc[8];
  #pragma unroll
  for (int j = 0; j < 8; ++j) acc[j] = 0.0f;

  union Cvt { float4 f4; half_t hx[8]; };

  if (nv <= 64){
    const int cnt = (e8 < nv) ? ((nv - e8 + 7) >> 3) : 0;
    // phase 1: edge indices (independent nt loads -- read once per layer)
    int sidx[8];
    #pragma unroll
    for (int j = 0; j < 8; ++j){
      int v = e8 + 8 * j;
      if (j < cnt)
        sidx[j] = (v == 0) ? node
                 : __builtin_nontemporal_load(sorted_src + beg + v - 1);
    }
    // phase 2: score gathers (temporal -- hot set)
    float sc[8];
    #pragma unroll
    for (int j = 0; j < 8; ++j){
      if (j < cnt){
        float s = s_src[sidx[j] * 8 + c8] + sdst;
        sc[j] = (s > 0.0f) ? s : NEG_SLOPE * s;
      }
    }
    // phase 2b: h gathers (temporal) before the butterfly
    float4 hraw[8];
    #pragma unroll
    for (int j = 0; j < 8; ++j){
      if (j < cnt)
        hraw[j] = *(const float4*)(h + (size_t)sidx[j] * 64 + c8 * 8);
    }
    // per-head max + butterfly
    #pragma unroll
    for (int j = 0; j < 8; ++j)
      if (j < cnt) m = fmaxf(m, sc[j]);
    m = fmaxf(m, __shfl_xor(m, 8, 64));
    m = fmaxf(m, __shfl_xor(m, 16, 64));
    m = fmaxf(m, __shfl_xor(m, 32, 64));
    // phase 3: convert + accumulate (pure VALU)
    #pragma unroll
    for (int j = 0; j < 8; ++j){
      if (j < cnt){
        float e = __expf(sc[j] - m);
        z += e;
        Cvt u; u.f4 = hraw[j];
        #pragma unroll
        for (int k = 0; k < 8; ++k)
          acc[k] = fmaf(e, (float)u.hx[k], acc[k]);
      }
    }
  } else {
    // slow streaming path (rare: nv > 64)
    for (int v = e8; v < nv; v += 8){
      int s = (v == 0) ? node : sorted_src[beg + v - 1];
      float scv = s_src[s * 8 + c8] + sdst;
      scv = (scv > 0.0f) ? scv : NEG_SLOPE * scv;
      m = fmaxf(m, scv);
    }
    m = fmaxf(m, __shfl_xor(m, 8, 64));
    m = fmaxf(m, __shfl_xor(m, 16, 64));
    m = fmaxf(m, __shfl_xor(m, 32, 64));
    for (int v = e8; v < nv; v += 8){
      int s = (v == 0) ? node : sorted_src[beg + v - 1];
      float scv = s_src[s * 8 + c8] + sdst;
      scv = (scv > 0.0f) ? scv : NEG_SLOPE * scv;
      float e = __expf(scv - m);
      z += e;
      Cvt u; u.f4 = *(const float4*)(h + (size_t)s * 64 + c8 * 8);
      #pragma unroll
      for (int k = 0; k < 8; ++k)
        acc[k] = fmaf(e, (float)u.hx[k], acc[k]);
    }
  }

  // butterfly reduce z + acc over the 8 e8-groups
  #pragma unroll
  for (int off = 8; off < 64; off <<= 1){
    z += __shfl_xor(z, off, 64);
    #pragma unroll
    for (int j = 0; j < 8; ++j) acc[j] += __shfl_xor(acc[j], off, 64);
  }

  if (e8 == 0){
    float inv = 1.0f / (z + 1e-16f);
    const float4* bp = (const float4*)(bias + c8 * 8);
    float4 b0 = bp[0], b1 = bp[1];
    f32x4 o0, o1;
    o0.x = acc[0] * inv + b0.x;
    o0.y = acc[1] * inv + b0.y;
    o0.z = acc[2] * inv + b0.z;
    o0.w = acc[3] * inv + b0.w;
    o1.x = acc[4] * inv + b1.x;
    o1.y = acc[5] * inv + b1.y;
    o1.z = acc[6] * inv + b1.z;
    o1.w = acc[7] * inv + b1.w;
    f32x4* op = (f32x4*)(out + (size_t)node * 64 + c8 * 8);
    __builtin_nontemporal_store(o0, op);        // streaming: don't evict hot set
    __builtin_nontemporal_store(o1, op + 1);
  }
}

// ---------------------------------------------------------------- launch
extern "C" void kernel_launch(void* const* d_in, const int* in_sizes, int n_in,
                              void* d_out, int out_size, void* d_ws, size_t ws_size,
                              hipStream_t stream){
  const float* x0   = (const float*)d_in[0];
  const int*   eidx = (const int*)  d_in[1];   // [2, E]
  const float* Ws   = (const float*)d_in[2];   // [L, 64, 64]
  const float* asrc = (const float*)d_in[3];   // [L, 8, 8]
  const float* adst = (const float*)d_in[4];   // [L, 8, 8]
  const float* bias = (const float*)d_in[5];   // [L, 64]

  const int N = in_sizes[0] / 64;
  const int E = in_sizes[1] / 2;
  const int L = in_sizes[2] / (64 * 64);

  char* ws = (char*)d_ws;
  size_t off = 0;
  auto alloc = [&](size_t bytes) -> void* {
    void* p = ws + off;
    off = (off + bytes + 255) & ~(size_t)255;
    return p;
  };
  half_t* hbuf   = (half_t*)alloc((size_t)N * 64 * sizeof(half_t));
  float* bufA    = (float*)alloc((size_t)N * 64 * sizeof(float));
  float* bufB    = (float*)alloc((size_t)N * 64 * sizeof(float));
  float* ssrc    = (float*)alloc((size_t)N * 8 * sizeof(float));
  float* sdstb   = (float*)alloc((size_t)N * 8 * sizeof(float));
  int*   counts  = (int*)alloc((size_t)N * sizeof(int));
  int*   offsets = (int*)alloc((size_t)(N + 1) * sizeof(int));
  int*   cursor  = (int*)alloc((size_t)N * sizeof(int));
  int*   ssorted = (int*)alloc((size_t)E * sizeof(int));

  const int* esrc = eidx;
  const int* edst = eidx + E;

  // CSR by destination — built once, reused by all layers
  zero_i32<<<ceil_div(N, 256), 256, 0, stream>>>(counts, N);
  hist_kernel<<<ceil_div(E, 1024), 256, 0, stream>>>(edst, counts, E);
  scan_kernel<<<1, 1024, 0, stream>>>(counts, offsets, cursor, N);
  scatter_kernel<<<ceil_div(E, 1024), 256, 0, stream>>>(esrc, edst, cursor, ssorted, E);

  float* bufs[2] = {bufA, bufB};
  for (int l = 0; l < L; ++l){
    const float* xin  = (l == 0)     ? x0 : bufs[(l - 1) & 1];
    float*       xout = (l == L - 1) ? (float*)d_out : bufs[l & 1];
    gemm_fused<<<ceil_div(N, 16), 256, 0, stream>>>(
        xin, Ws + (size_t)l * 64 * 64, asrc + l * 64, adst + l * 64,
        hbuf, ssrc, sdstb, N);
    aggregate<<<ceil_div(N * 64, 256), 256, 0, stream>>>(
        hbuf, ssrc, sdstb, offsets, ssorted, bias + l * 64, xout, N, E);
  }
}